// Round 14
// baseline (80.173 us; speedup 1.0000x reference)
//
#include <hip/hip_runtime.h>
#include <hip/hip_bf16.h>

typedef unsigned short u16;
typedef unsigned int u32;
typedef unsigned char u8;
typedef long i64;
typedef __bf16 bf16x8 __attribute__((ext_vector_type(8)));
typedef float floatx4 __attribute__((ext_vector_type(4)));
typedef float f32x4 __attribute__((ext_vector_type(4)));

#define MFMA16(a,b,c) __builtin_amdgcn_mfma_f32_16x16x32_bf16((a),(b),(c),0,0,0)
#define MFMA8(a,b,c)  __builtin_amdgcn_mfma_f32_16x16x32_fp8_fp8((a),(b),(c),0,0,0)
#define AS1 __attribute__((address_space(1)))
#define AS3 __attribute__((address_space(3)))
#define VM5 asm volatile("s_waitcnt vmcnt(5)" ::: "memory")
#define VM3 asm volatile("s_waitcnt vmcnt(3)" ::: "memory")
#define VM0 asm volatile("s_waitcnt vmcnt(0)" ::: "memory")
#define SBAR __builtin_amdgcn_s_barrier()
#define SCHED0 __builtin_amdgcn_sched_barrier(0)

__device__ __forceinline__ void gl16(const void* g, void* l){
  __builtin_amdgcn_global_load_lds((const AS1 void*)g, (AS3 void*)l, 16, 0, 0);
}
__device__ __forceinline__ u16 f2bf(float f){
  u32 u = __builtin_bit_cast(u32, f);
  u += 0x7FFFu + ((u >> 16) & 1u);
  return (u16)(u >> 16);
}
__device__ __forceinline__ float bf2f(u16 h){
  u32 u = ((u32)h) << 16;
  return __builtin_bit_cast(float, u);
}
__device__ __forceinline__ bf16x8 ldfrag(const u16* p){
  return *(const bf16x8*)p;
}
__device__ __forceinline__ u32 pk4(float a, float b, float c, float d){
  int r = __builtin_amdgcn_cvt_pk_fp8_f32(a, b, 0, false);
  r = __builtin_amdgcn_cvt_pk_fp8_f32(c, d, r, true);
  return (u32)r;
}
// swizzled fp8 fragment read (verified R8): chunk = rows x 64 cols,
// superrow(2 rows)=128B, 16B-granule XOR
__device__ __forceinline__ i64 ldA8(const char* chunk, int r, int kf, int lg){
  int sr = r >> 1;
  int G = (((r&1)<<2) + (kf<<1) + (lg>>1)) ^ (sr&7);
  return *(const i64*)(chunk + sr*128 + G*16 + (lg&1)*8);
}

// ================ KP3: X staging + weight prep + adj fp8 convert ============
// blk [0,256): X; [256,544): weights; [544,4640): adj tiles (single 64x64 each)
__global__ __launch_bounds__(256) void kp3_prep(
    const float* __restrict__ inp, const float* __restrict__ hx,
    const float* __restrict__ adj,
    const float* __restrict__ W0, const float* __restrict__ b0,
    const float* __restrict__ W1, const float* __restrict__ b1,
    const float* __restrict__ Wc0, const float* __restrict__ bc0,
    const float* __restrict__ Wc1, const float* __restrict__ bc1,
    u16* __restrict__ WgT, u16* __restrict__ WcT,
    float* __restrict__ bias_g, float* __restrict__ bias_c,
    u8* __restrict__ adjf8, u8* __restrict__ adjTf8,
    u8* __restrict__ Xtf8, u16* __restrict__ XC2){
  __shared__ __align__(16) char sh[40960];
  int t = threadIdx.x;
  int blk = blockIdx.x;
  if (blk < 256) {
    float (*XT)[80] = (float(*)[80])sh;
    int r = t >> 2, fq = t & 3;
    int row = blk*64 + r;
    const float4* ip = (const float4*)(inp + (size_t)row*64 + fq*16);
    const float4* hp = (const float4*)(hx  + (size_t)row*64 + fq*16);
    float iv[16], hv[16];
    #pragma unroll
    for (int q=0;q<4;q++){
      float4 a = ip[q]; iv[4*q]=a.x; iv[4*q+1]=a.y; iv[4*q+2]=a.z; iv[4*q+3]=a.w;
      float4 c = hp[q]; hv[4*q]=c.x; hv[4*q+1]=c.y; hv[4*q+2]=c.z; hv[4*q+3]=c.w;
    }
    u32 pi[8];
    #pragma unroll
    for (int q=0;q<8;q++)
      pi[q] = (u32)f2bf(iv[2*q]) | ((u32)f2bf(iv[2*q+1])<<16);
    size_t rbase = (size_t)row*384;
    *(uint4*)(XC2 + rbase + fq*16)     = make_uint4(pi[0],pi[1],pi[2],pi[3]);
    *(uint4*)(XC2 + rbase + fq*16 + 8) = make_uint4(pi[4],pi[5],pi[6],pi[7]);
    #pragma unroll
    for (int q=0;q<16;q++){
      XT[fq*16+q][r]    = iv[q];
      XT[64+fq*16+q][r] = hv[q];
    }
    __syncthreads();
    int feat = t >> 1, half = t & 1;
    int b = blk >> 4, n0 = (blk & 15)*64;
    const float* src = &XT[feat][half*32];
    u32 o[8];
    #pragma unroll
    for (int p=0;p<8;p++)
      o[p] = pk4(src[4*p],src[4*p+1],src[4*p+2],src[4*p+3]);
    u8* dst = Xtf8 + (size_t)b*131072 + (size_t)feat*1024 + n0 + half*32;
    *(uint4*)dst      = make_uint4(o[0],o[1],o[2],o[3]);
    *(uint4*)(dst+16) = make_uint4(o[4],o[5],o[6],o[7]);
    return;
  }
  if (blk < 544) {
    int id = (blk - 256)*256 + t;
    if (id < 128*384) {
      int n = id / 384, k = id % 384;
      float v;
      if (k < 128)       v = W0[(k*3+0)*128 + n] + W1[(k*3+0)*128 + n];
      else if (k < 256){ int f = k-128; v = W0[(f*3+1)*128+n] + W0[(f*3+2)*128+n]; }
      else             { int f = k-256; v = W1[(f*3+1)*128+n] + W1[(f*3+2)*128+n]; }
      WgT[(size_t)n*384 + k] = f2bf(v);
    } else {
      int id2 = id - 128*384;
      int n = id2 / 384, k = id2 % 384;
      float v;
      if (k < 128)       v = Wc0[(k*3+0)*64 + n] + Wc1[(k*3+0)*64 + n];
      else if (k < 256){ int f = k-128; v = Wc0[(f*3+1)*64+n] + Wc0[(f*3+2)*64+n]; }
      else             { int f = k-256; v = Wc1[(f*3+1)*64+n] + Wc1[(f*3+2)*64+n]; }
      WcT[(size_t)n*384 + k] = f2bf(v);
    }
    if (blk == 256) {
      if (t < 128) bias_g[t] = b0[t] + b1[t];
      if (t < 64)  bias_c[t] = bc0[t] + bc1[t];
    }
    return;
  }
  // ---- adj: f32 -> fp8 copy + transposed fp8 copy; one 64x64 tile per block
  // nontemporal reads: adj is dead after this pass — don't evict the live
  // fp8 working set from L2/L3.
  u8* ltb = (u8*)sh;
  int blk2 = blk - 544;                 // 0..4095
  int b = blk2 >> 8;                    // batch
  int st = (blk2 >> 4) & 15;            // 64-row stripe
  int c = blk2 & 15;                    // 64-col tile
  int i0 = st*64, j0 = c*64;
  int r = t >> 2, cq = t & 3;
  size_t base = (size_t)b << 20;
  const f32x4* s4 = (const f32x4*)(adj + base + (size_t)(i0 + r)*1024 + j0 + (cq<<4));
  float v[16];
  #pragma unroll
  for (int q = 0; q < 4; q++) {
    f32x4 f = __builtin_nontemporal_load(&s4[q]);
    v[4*q]=f.x; v[4*q+1]=f.y; v[4*q+2]=f.z; v[4*q+3]=f.w;
  }
  u32 pk[4];
  #pragma unroll
  for (int p = 0; p < 4; p++)
    pk[p] = pk4(v[4*p],v[4*p+1],v[4*p+2],v[4*p+3]);
  *(uint4*)(adjf8 + base + (size_t)(i0 + r)*1024 + j0 + (cq<<4)) =
    make_uint4(pk[0],pk[1],pk[2],pk[3]);
  #pragma unroll
  for (int q = 0; q < 16; q++)
    ltb[(cq*16+q)*72 + r] = (u8)(pk[q>>2] >> ((q&3)*8));
  __syncthreads();
  u32 w4[4];
  #pragma unroll
  for (int p = 0; p < 4; p++){
    u32 b0v = ltb[r*72 + cq*16 + 4*p];
    u32 b1v = ltb[r*72 + cq*16 + 4*p+1];
    u32 b2v = ltb[r*72 + cq*16 + 4*p+2];
    u32 b3v = ltb[r*72 + cq*16 + 4*p+3];
    w4[p] = b0v | (b1v<<8) | (b2v<<16) | (b3v<<24);
  }
  *(uint4*)(adjTf8 + base + (size_t)(j0 + r)*1024 + i0 + (cq<<4)) =
    make_uint4(w4[0],w4[1],w4[2],w4[3]);
}

// ================ KG2: fp8 diffusion + gates; 16-row tiles, grid 1024 =======
// LDS 40KB: A0 2x2K @0 | A1 2x2K @4096 | B 2x16K @8192
// u-gate stored bf16 in XC2 cols 320:384 (otherwise-unused)
__global__ __launch_bounds__(256) void kg2_gates(
    const u8* __restrict__ adjf8, const u8* __restrict__ adjTf8,
    const u8* __restrict__ Xtf8,
    const float* __restrict__ inp, const float* __restrict__ hx,
    const u16* __restrict__ WgT, const float* __restrict__ bias_g,
    u16* __restrict__ XC2, u8* __restrict__ Stf8){
  __shared__ __align__(16) char lds[40960];
  int bid = ((blockIdx.x & 7) << 7) | (blockIdx.x >> 3);   // XCD swizzle 1024=8*128
  int mt = bid & 63, b = bid >> 6;
  int t = threadIdx.x, w = t>>6, l = t&63, lr = l&15, lg = l>>4;
  int gp = (l&7) ^ ((l>>3)&7);
  size_t off = (size_t)(2*(l>>3) + (gp>>2))*1024 + (gp&3)*16;
  const u8* A0g = adjf8  + ((size_t)b<<20) + (size_t)mt*16384 + off;
  const u8* A1g = adjTf8 + ((size_t)b<<20) + (size_t)mt*16384 + off;
  const u8* Bg  = Xtf8 + (size_t)b*131072 + off;
  floatx4 acc0[2] = {}, acc1[2] = {}, s0 = {}, s1 = {};
  const i64 ONES = 0x3838383838383838L;
  #define STG_KG(bi, kk) do{ \
    if (w==0){ \
      gl16(A0g+(kk),          lds+(bi)*2048); \
      gl16(A0g+(kk)+64,       lds+(bi)*2048+1024); \
      gl16(Bg+(kk),           lds+8192+(bi)*16384); \
      gl16(Bg+(kk)+16384,     lds+8192+(bi)*16384+1024); \
      gl16(Bg+(kk)+32768,     lds+8192+(bi)*16384+2048); \
    } else if (w==1){ \
      gl16(A1g+(kk),          lds+4096+(bi)*2048); \
      gl16(A1g+(kk)+64,       lds+4096+(bi)*2048+1024); \
      gl16(Bg+(kk)+49152,     lds+8192+(bi)*16384+3072); \
      gl16(Bg+(kk)+65536,     lds+8192+(bi)*16384+4096); \
      gl16(Bg+(kk)+81920,     lds+8192+(bi)*16384+5120); \
    } else if (w==2){ \
      gl16(Bg+(kk)+98304,     lds+8192+(bi)*16384+6144); \
      gl16(Bg+(kk)+114688,    lds+8192+(bi)*16384+7168); \
      gl16(Bg+(kk)+64,        lds+8192+(bi)*16384+8192); \
      gl16(Bg+(kk)+64+16384,  lds+8192+(bi)*16384+9216); \
      gl16(Bg+(kk)+64+32768,  lds+8192+(bi)*16384+10240); \
    } else { \
      gl16(Bg+(kk)+64+49152,  lds+8192+(bi)*16384+11264); \
      gl16(Bg+(kk)+64+65536,  lds+8192+(bi)*16384+12288); \
      gl16(Bg+(kk)+64+81920,  lds+8192+(bi)*16384+13312); \
      gl16(Bg+(kk)+64+98304,  lds+8192+(bi)*16384+14336); \
      gl16(Bg+(kk)+64+114688, lds+8192+(bi)*16384+15360); \
    } \
  }while(0)
  STG_KG(0, 0);
  int cur = 0;
  for (int step = 0; step < 8; ++step){
    if (step < 7) { STG_KG(cur^1, (step+1)*128); VM5; } else { VM0; }
    SBAR; SCHED0;
    const char* A0b = lds + cur*2048;
    const char* A1b = lds + 4096 + cur*2048;
    const char* Bb  = lds + 8192 + cur*16384;
    #pragma unroll
    for (int kf=0; kf<4; kf++){
      int co = kf >> 1, kl = kf & 1;
      i64 a0 = ldA8(A0b + co*1024, lr, kl, lg);
      i64 a1 = ldA8(A1b + co*1024, lr, kl, lg);
      s0 = MFMA8(a0, ONES, s0);
      s1 = MFMA8(a1, ONES, s1);
      #pragma unroll
      for (int nf=0; nf<2; nf++){
        i64 bb = ldA8(Bb + co*8192, w*32 + nf*16 + lr, kl, lg);
        acc0[nf] = MFMA8(a0, bb, acc0[nf]);
        acc1[nf] = MFMA8(a1, bb, acc1[nf]);
      }
    }
    SCHED0; SBAR;
    cur ^= 1;
  }
  #undef STG_KG
  __syncthreads();
  // ---- epilogue: SL[16][392] = [x | Y0 | Y1] ----
  u16* SL = (u16*)lds;
  u16* SLT = (u16*)(lds + 12544);   // [64][16]
  float d0i[4], d1i[4];
  #pragma unroll
  for (int rr=0; rr<4; rr++){
    d1i[rr] = 1.0f / (s0[rr] + 1.0f);   // adj row sums -> d1
    d0i[rr] = 1.0f / (s1[rr] + 1.0f);   // adj col sums -> d0
  }
  #pragma unroll
  for (int nf = 0; nf < 2; nf++) {
    #pragma unroll
    for (int rr = 0; rr < 4; rr++) {
      int rl = lg*4 + rr;
      int row = mt*16 + rl;
      int col = w*32 + nf*16 + lr;
      float xv = (col < 64) ? inp[(size_t)(b*1024+row)*64 + col]
                            : hx [(size_t)(b*1024+row)*64 + (col-64)];
      float y0 = (acc0[nf][rr] + xv) * d0i[rr];
      float y1 = (acc1[nf][rr] + xv) * d1i[rr];
      u16 b0v = f2bf(y0), b1v = f2bf(y1);
      SL[rl*392 + col]       = f2bf(xv);
      SL[rl*392 + 128 + col] = b0v;
      SL[rl*392 + 256 + col] = b1v;
      if (col < 64) {
        size_t grow = (size_t)(b*1024 + row)*384;
        XC2[grow + 128 + col] = b0v;
        XC2[grow + 256 + col] = b1v;
      }
    }
  }
  __syncthreads();
  // ---- gates GEMM: 16x384 @ 384x128 ----
  floatx4 g[2] = {};
  for (int kk = 0; kk < 384; kk += 32) {
    int ko = kk + lg*8;
    bf16x8 a = ldfrag(&SL[(size_t)lr*392 + ko]);
    #pragma unroll
    for (int nf = 0; nf < 2; nf++)
      g[nf] = MFMA16(a, ldfrag(WgT + (size_t)(w*32+nf*16+lr)*384 + ko), g[nf]);
  }
  __syncthreads();
  #pragma unroll
  for (int nf = 0; nf < 2; nf++) {
    #pragma unroll
    for (int rr = 0; rr < 4; rr++) {
      int rl = lg*4 + rr;
      int row = mt*16 + rl;
      int col = w*32 + nf*16 + lr;
      float pre = g[nf][rr] + bias_g[col];
      float s = 1.0f / (1.0f + __expf(-pre));
      if (col < 64) {          // r gate -> S = r*hx
        float shv = s * hx[(size_t)(b*1024+row)*64 + col];
        u16 bv = f2bf(shv);
        XC2[(size_t)(b*1024+row)*384 + 64 + col] = bv;
        SLT[col*16 + rl] = bv;
      } else {                 // u gate -> XC2 cols 320:384 (bf16)
        XC2[(size_t)(b*1024+row)*384 + 320 + (col-64)] = f2bf(s);
      }
    }
  }
  __syncthreads();
  // Stf8 writeout (feature-major fp8)
  {
    int feat = t >> 2, q = t & 3;
    uint2 vv = *(const uint2*)&SLT[feat*16 + q*4];
    float f0 = bf2f((u16)(vv.x & 0xFFFF)), f1 = bf2f((u16)(vv.x >> 16));
    float f2 = bf2f((u16)(vv.y & 0xFFFF)), f3 = bf2f((u16)(vv.y >> 16));
    *(u32*)(Stf8 + (size_t)b*65536 + (size_t)feat*1024 + mt*16 + q*4) =
      pk4(f0,f1,f2,f3);
  }
}

// ================ KZ2: fp8 Z diffusion + candidate + GRU; 16-row tiles ======
// LDS 24KB: A0 2x2K @0 | A1 2x2K @4096 | B 2x8K @8192
__global__ __launch_bounds__(256) void kz2_cand(
    const u8* __restrict__ adjf8, const u8* __restrict__ adjTf8,
    const u8* __restrict__ Stf8,
    const u16* __restrict__ XC2, const u16* __restrict__ WcT,
    const float* __restrict__ bias_c,
    const float* __restrict__ hx, float* __restrict__ out){
  __shared__ __align__(16) char lds[24576];
  int bid = ((blockIdx.x & 7) << 7) | (blockIdx.x >> 3);
  int mt = bid & 63, b = bid >> 6;
  int t = threadIdx.x, w = t>>6, l = t&63, lr = l&15, lg = l>>4;
  int gp = (l&7) ^ ((l>>3)&7);
  size_t off = (size_t)(2*(l>>3) + (gp>>2))*1024 + (gp&3)*16;
  const u8* A0g = adjf8  + ((size_t)b<<20) + (size_t)mt*16384 + off;
  const u8* A1g = adjTf8 + ((size_t)b<<20) + (size_t)mt*16384 + off;
  const u8* Bg  = Stf8 + (size_t)b*65536 + off;
  floatx4 z0 = {}, z1 = {}, s0 = {}, s1 = {};
  const i64 ONES = 0x3838383838383838L;
  #define STG_KZ(bi, kk) do{ \
    if (w==0){ \
      gl16(A0g+(kk),         lds+(bi)*2048); \
      gl16(A0g+(kk)+64,      lds+(bi)*2048+1024); \
      gl16(Bg+(kk),          lds+8192+(bi)*8192); \
    } else if (w==1){ \
      gl16(A1g+(kk),         lds+4096+(bi)*2048); \
      gl16(A1g+(kk)+64,      lds+4096+(bi)*2048+1024); \
      gl16(Bg+(kk)+16384,    lds+8192+(bi)*8192+1024); \
    } else if (w==2){ \
      gl16(Bg+(kk)+32768,    lds+8192+(bi)*8192+2048); \
      gl16(Bg+(kk)+49152,    lds+8192+(bi)*8192+3072); \
      gl16(Bg+(kk)+64,       lds+8192+(bi)*8192+4096); \
    } else { \
      gl16(Bg+(kk)+64+16384, lds+8192+(bi)*8192+5120); \
      gl16(Bg+(kk)+64+32768, lds+8192+(bi)*8192+6144); \
      gl16(Bg+(kk)+64+49152, lds+8192+(bi)*8192+7168); \
    } \
  }while(0)
  STG_KZ(0, 0);
  int cur = 0;
  for (int step = 0; step < 8; ++step){
    if (step < 7) { STG_KZ(cur^1, (step+1)*128); VM3; } else { VM0; }
    SBAR; SCHED0;
    const char* A0b = lds + cur*2048;
    const char* A1b = lds + 4096 + cur*2048;
    const char* Bb  = lds + 8192 + cur*8192;
    #pragma unroll
    for (int kf=0; kf<4; kf++){
      int co = kf >> 1, kl = kf & 1;
      i64 a0 = ldA8(A0b + co*1024, lr, kl, lg);
      i64 a1 = ldA8(A1b + co*1024, lr, kl, lg);
      s0 = MFMA8(a0, ONES, s0);
      s1 = MFMA8(a1, ONES, s1);
      i64 bb = ldA8(Bb + co*4096, w*16 + lr, kl, lg);
      z0 = MFMA8(a0, bb, z0);
      z1 = MFMA8(a1, bb, z1);
    }
    SCHED0; SBAR;
    cur ^= 1;
  }
  #undef STG_KZ
  __syncthreads();
  // ---- SL[16][392] = [x|S | Y0inp|Z0 | Y1inp|Z1]; loader skips Z col ranges
  u16* SL = (u16*)lds;
  {
    int rl = t >> 4, s = t & 15;
    size_t grow = (size_t)(b*1024 + mt*16 + rl)*384;
    size_t base = (size_t)rl*392;
    #pragma unroll
    for (int j = 0; j < 3; j++)            // cols 0..191
      *(uint2*)&SL[base + s*12 + j*4] = *(const uint2*)(XC2 + grow + s*12 + j*4);
    *(uint2*)&SL[base + 256 + s*4] = *(const uint2*)(XC2 + grow + 256 + s*4);
  }
  float d0i[4], d1i[4];
  #pragma unroll
  for (int rr=0; rr<4; rr++){
    d1i[rr] = 1.0f / (s0[rr] + 1.0f);
    d0i[rr] = 1.0f / (s1[rr] + 1.0f);
  }
  __syncthreads();
  #pragma unroll
  for (int rr = 0; rr < 4; rr++) {
    int rl = lg*4 + rr;
    int col = w*16 + lr;
    float sval = bf2f(SL[rl*392 + 64 + col]);
    SL[rl*392 + 192 + col] = f2bf((z0[rr] + sval) * d0i[rr]);
    SL[rl*392 + 320 + col] = f2bf((z1[rr] + sval) * d1i[rr]);
  }
  __syncthreads();
  // ---- candidate GEMM 16x384 @ 384x64 + tanh + GRU ----
  floatx4 c = {};
  for (int kk = 0; kk < 384; kk += 32) {
    int ko = kk + lg*8;
    bf16x8 a = ldfrag(&SL[(size_t)lr*392 + ko]);
    c = MFMA16(a, ldfrag(WcT + (size_t)(w*16+lr)*384 + ko), c);
  }
  #pragma unroll
  for (int rr = 0; rr < 4; rr++) {
    int row = mt*16 + lg*4 + rr;
    int col = w*16 + lr;
    float pre = c[rr] + bias_c[col];
    pre = fminf(fmaxf(pre, -15.f), 15.f);
    float e2 = __expf(2.0f*pre);
    float cv = (e2 - 1.0f) / (e2 + 1.0f);
    float u = bf2f(XC2[(size_t)(b*1024+row)*384 + 320 + col]);
    float h = hx[(size_t)(b*1024+row)*64 + col];
    out[(size_t)(b*1024+row)*64 + col] = u*h + (1.0f - u)*cv;
  }
}

extern "C" void kernel_launch(void* const* d_in, const int* in_sizes, int n_in,
                              void* d_out, int out_size, void* d_ws, size_t ws_size,
                              hipStream_t stream) {
  (void)in_sizes; (void)n_in; (void)out_size; (void)ws_size;
  const float* inp = (const float*)d_in[0];
  const float* hx  = (const float*)d_in[1];
  const float* adj = (const float*)d_in[2];
  const float* W0  = (const float*)d_in[3];
  const float* b0  = (const float*)d_in[4];
  const float* W1  = (const float*)d_in[5];
  const float* b1  = (const float*)d_in[6];
  const float* Wc0 = (const float*)d_in[7];
  const float* bc0 = (const float*)d_in[8];
  const float* Wc1 = (const float*)d_in[9];
  const float* bc1 = (const float*)d_in[10];
  float* out = (float*)d_out;
  char* ws = (char*)d_ws;

  u8* adjf8   = (u8*)(ws + 0);                 // 16777216
  u8* adjTf8  = (u8*)(ws + 16777216);          // 16777216
  u8* Xtf8    = (u8*)(ws + 33554432);          // 2097152
  u16* XC2    = (u16*)(ws + 35651584);         // 12582912
  u8* Stf8    = (u8*)(ws + 48234496);          // 1048576
  u16* WgT    = (u16*)(ws + 49283072);         // 98304
  u16* WcT    = (u16*)(ws + 49381376);         // 49152
  float* bias_g = (float*)(ws + 49430528);     // 512
  float* bias_c = (float*)(ws + 49431040);     // 256

  hipLaunchKernelGGL(kp3_prep, dim3(4640), dim3(256), 0, stream,
                     inp, hx, adj, W0, b0, W1, b1, Wc0, bc0, Wc1, bc1,
                     WgT, WcT, bias_g, bias_c, adjf8, adjTf8, Xtf8, XC2);
  hipLaunchKernelGGL(kg2_gates, dim3(1024), dim3(256), 0, stream,
                     adjf8, adjTf8, Xtf8, inp, hx, WgT, bias_g, XC2, Stf8);
  hipLaunchKernelGGL(kz2_cand, dim3(1024), dim3(256), 0, stream,
                     adjf8, adjTf8, Stf8, XC2, WcT, bias_c, hx, out);
}

// Round 15
// 64.753 us; speedup vs baseline: 1.2381x; 1.2381x over previous
//
#include <hip/hip_runtime.h>
#include <hip/hip_bf16.h>

typedef unsigned short u16;
typedef unsigned int u32;
typedef unsigned char u8;
typedef long i64;
typedef __bf16 bf16x8 __attribute__((ext_vector_type(8)));
typedef float floatx4 __attribute__((ext_vector_type(4)));

#define MFMA16(a,b,c) __builtin_amdgcn_mfma_f32_16x16x32_bf16((a),(b),(c),0,0,0)
#define MFMA8(a,b,c)  __builtin_amdgcn_mfma_f32_16x16x32_fp8_fp8((a),(b),(c),0,0,0)
#define AS1 __attribute__((address_space(1)))
#define AS3 __attribute__((address_space(3)))
#define VM5 asm volatile("s_waitcnt vmcnt(5)" ::: "memory")
#define VM3 asm volatile("s_waitcnt vmcnt(3)" ::: "memory")
#define VM0 asm volatile("s_waitcnt vmcnt(0)" ::: "memory")
#define SBAR __builtin_amdgcn_s_barrier()
#define SCHED0 __builtin_amdgcn_sched_barrier(0)

__device__ __forceinline__ void gl16(const void* g, void* l){
  __builtin_amdgcn_global_load_lds((const AS1 void*)g, (AS3 void*)l, 16, 0, 0);
}
__device__ __forceinline__ u16 f2bf(float f){
  u32 u = __builtin_bit_cast(u32, f);
  u += 0x7FFFu + ((u >> 16) & 1u);
  return (u16)(u >> 16);
}
__device__ __forceinline__ float bf2f(u16 h){
  u32 u = ((u32)h) << 16;
  return __builtin_bit_cast(float, u);
}
__device__ __forceinline__ bf16x8 ldfrag(const u16* p){
  return *(const bf16x8*)p;
}
__device__ __forceinline__ u32 pk4(float a, float b, float c, float d){
  int r = __builtin_amdgcn_cvt_pk_fp8_f32(a, b, 0, false);
  r = __builtin_amdgcn_cvt_pk_fp8_f32(c, d, r, true);
  return (u32)r;
}
// swizzled fp8 fragment read (verified R8): chunk = rows x 64 cols,
// superrow(2 rows)=128B, 16B-granule XOR
__device__ __forceinline__ i64 ldA8(const char* chunk, int r, int kf, int lg){
  int sr = r >> 1;
  int G = (((r&1)<<2) + (kf<<1) + (lg>>1)) ^ (sr&7);
  return *(const i64*)(chunk + sr*128 + G*16 + (lg&1)*8);
}

// ================ KP3: X staging + weight prep + adj fp8 convert ============
// blk [0,256): X; [256,544): weights; [544,4640): adj tiles (single 64x64 each)
__global__ __launch_bounds__(256) void kp3_prep(
    const float* __restrict__ inp, const float* __restrict__ hx,
    const float* __restrict__ adj,
    const float* __restrict__ W0, const float* __restrict__ b0,
    const float* __restrict__ W1, const float* __restrict__ b1,
    const float* __restrict__ Wc0, const float* __restrict__ bc0,
    const float* __restrict__ Wc1, const float* __restrict__ bc1,
    u16* __restrict__ WgT, u16* __restrict__ WcT,
    float* __restrict__ bias_g, float* __restrict__ bias_c,
    u8* __restrict__ adjf8, u8* __restrict__ adjTf8,
    u8* __restrict__ Xtf8, u16* __restrict__ XC2){
  __shared__ __align__(16) char sh[40960];
  int t = threadIdx.x;
  int blk = blockIdx.x;
  if (blk < 256) {
    float (*XT)[80] = (float(*)[80])sh;
    int r = t >> 2, fq = t & 3;
    int row = blk*64 + r;
    const float4* ip = (const float4*)(inp + (size_t)row*64 + fq*16);
    const float4* hp = (const float4*)(hx  + (size_t)row*64 + fq*16);
    float iv[16], hv[16];
    #pragma unroll
    for (int q=0;q<4;q++){
      float4 a = ip[q]; iv[4*q]=a.x; iv[4*q+1]=a.y; iv[4*q+2]=a.z; iv[4*q+3]=a.w;
      float4 c = hp[q]; hv[4*q]=c.x; hv[4*q+1]=c.y; hv[4*q+2]=c.z; hv[4*q+3]=c.w;
    }
    u32 pi[8];
    #pragma unroll
    for (int q=0;q<8;q++)
      pi[q] = (u32)f2bf(iv[2*q]) | ((u32)f2bf(iv[2*q+1])<<16);
    size_t rbase = (size_t)row*384;
    *(uint4*)(XC2 + rbase + fq*16)     = make_uint4(pi[0],pi[1],pi[2],pi[3]);
    *(uint4*)(XC2 + rbase + fq*16 + 8) = make_uint4(pi[4],pi[5],pi[6],pi[7]);
    #pragma unroll
    for (int q=0;q<16;q++){
      XT[fq*16+q][r]    = iv[q];
      XT[64+fq*16+q][r] = hv[q];
    }
    __syncthreads();
    int feat = t >> 1, half = t & 1;
    int b = blk >> 4, n0 = (blk & 15)*64;
    const float* src = &XT[feat][half*32];
    u32 o[8];
    #pragma unroll
    for (int p=0;p<8;p++)
      o[p] = pk4(src[4*p],src[4*p+1],src[4*p+2],src[4*p+3]);
    u8* dst = Xtf8 + (size_t)b*131072 + (size_t)feat*1024 + n0 + half*32;
    *(uint4*)dst      = make_uint4(o[0],o[1],o[2],o[3]);
    *(uint4*)(dst+16) = make_uint4(o[4],o[5],o[6],o[7]);
    return;
  }
  if (blk < 544) {
    int id = (blk - 256)*256 + t;
    if (id < 128*384) {
      int n = id / 384, k = id % 384;
      float v;
      if (k < 128)       v = W0[(k*3+0)*128 + n] + W1[(k*3+0)*128 + n];
      else if (k < 256){ int f = k-128; v = W0[(f*3+1)*128+n] + W0[(f*3+2)*128+n]; }
      else             { int f = k-256; v = W1[(f*3+1)*128+n] + W1[(f*3+2)*128+n]; }
      WgT[(size_t)n*384 + k] = f2bf(v);
    } else {
      int id2 = id - 128*384;
      int n = id2 / 384, k = id2 % 384;
      float v;
      if (k < 128)       v = Wc0[(k*3+0)*64 + n] + Wc1[(k*3+0)*64 + n];
      else if (k < 256){ int f = k-128; v = Wc0[(f*3+1)*64+n] + Wc0[(f*3+2)*64+n]; }
      else             { int f = k-256; v = Wc1[(f*3+1)*64+n] + Wc1[(f*3+2)*64+n]; }
      WcT[(size_t)n*384 + k] = f2bf(v);
    }
    if (blk == 256) {
      if (t < 128) bias_g[t] = b0[t] + b1[t];
      if (t < 64)  bias_c[t] = bc0[t] + bc1[t];
    }
    return;
  }
  // ---- adj: f32 -> fp8 copy + transposed fp8 copy; one 64x64 tile per block
  u8* ltb = (u8*)sh;
  int blk2 = blk - 544;                 // 0..4095
  int b = blk2 >> 8;                    // batch
  int st = (blk2 >> 4) & 15;            // 64-row stripe
  int c = blk2 & 15;                    // 64-col tile
  int i0 = st*64, j0 = c*64;
  int r = t >> 2, cq = t & 3;
  size_t base = (size_t)b << 20;
  const float4* s4 = (const float4*)(adj + base + (size_t)(i0 + r)*1024 + j0 + (cq<<4));
  float v[16];
  #pragma unroll
  for (int q = 0; q < 4; q++) {
    float4 f = s4[q];
    v[4*q]=f.x; v[4*q+1]=f.y; v[4*q+2]=f.z; v[4*q+3]=f.w;
  }
  u32 pk[4];
  #pragma unroll
  for (int p = 0; p < 4; p++)
    pk[p] = pk4(v[4*p],v[4*p+1],v[4*p+2],v[4*p+3]);
  *(uint4*)(adjf8 + base + (size_t)(i0 + r)*1024 + j0 + (cq<<4)) =
    make_uint4(pk[0],pk[1],pk[2],pk[3]);
  #pragma unroll
  for (int q = 0; q < 16; q++)
    ltb[(cq*16+q)*72 + r] = (u8)(pk[q>>2] >> ((q&3)*8));
  __syncthreads();
  u32 w4[4];
  #pragma unroll
  for (int p = 0; p < 4; p++){
    u32 b0v = ltb[r*72 + cq*16 + 4*p];
    u32 b1v = ltb[r*72 + cq*16 + 4*p+1];
    u32 b2v = ltb[r*72 + cq*16 + 4*p+2];
    u32 b3v = ltb[r*72 + cq*16 + 4*p+3];
    w4[p] = b0v | (b1v<<8) | (b2v<<16) | (b3v<<24);
  }
  *(uint4*)(adjTf8 + base + (size_t)(j0 + r)*1024 + i0 + (cq<<4)) =
    make_uint4(w4[0],w4[1],w4[2],w4[3]);
}

// ================ KG2: fp8 diffusion + gates; 16-row tiles, grid 1024 =======
// LDS 40KB: A0 2x2K @0 | A1 2x2K @4096 | B 2x16K @8192
__global__ __launch_bounds__(256) void kg2_gates(
    const u8* __restrict__ adjf8, const u8* __restrict__ adjTf8,
    const u8* __restrict__ Xtf8,
    const float* __restrict__ inp, const float* __restrict__ hx,
    const u16* __restrict__ WgT, const float* __restrict__ bias_g,
    u16* __restrict__ XC2, u8* __restrict__ Stf8, float* __restrict__ uBuf){
  __shared__ __align__(16) char lds[40960];
  int bid = ((blockIdx.x & 7) << 7) | (blockIdx.x >> 3);   // XCD swizzle 1024=8*128
  int mt = bid & 63, b = bid >> 6;
  int t = threadIdx.x, w = t>>6, l = t&63, lr = l&15, lg = l>>4;
  int gp = (l&7) ^ ((l>>3)&7);
  size_t off = (size_t)(2*(l>>3) + (gp>>2))*1024 + (gp&3)*16;
  const u8* A0g = adjf8  + ((size_t)b<<20) + (size_t)mt*16384 + off;
  const u8* A1g = adjTf8 + ((size_t)b<<20) + (size_t)mt*16384 + off;
  const u8* Bg  = Xtf8 + (size_t)b*131072 + off;
  floatx4 acc0[2] = {}, acc1[2] = {}, s0 = {}, s1 = {};
  const i64 ONES = 0x3838383838383838L;
  // per stage 20 gl16 (5/wave): A chunks 1KB, B f-blocks f*16384 global, chunks +64
  #define STG_KG(bi, kk) do{ \
    if (w==0){ \
      gl16(A0g+(kk),          lds+(bi)*2048); \
      gl16(A0g+(kk)+64,       lds+(bi)*2048+1024); \
      gl16(Bg+(kk),           lds+8192+(bi)*16384); \
      gl16(Bg+(kk)+16384,     lds+8192+(bi)*16384+1024); \
      gl16(Bg+(kk)+32768,     lds+8192+(bi)*16384+2048); \
    } else if (w==1){ \
      gl16(A1g+(kk),          lds+4096+(bi)*2048); \
      gl16(A1g+(kk)+64,       lds+4096+(bi)*2048+1024); \
      gl16(Bg+(kk)+49152,     lds+8192+(bi)*16384+3072); \
      gl16(Bg+(kk)+65536,     lds+8192+(bi)*16384+4096); \
      gl16(Bg+(kk)+81920,     lds+8192+(bi)*16384+5120); \
    } else if (w==2){ \
      gl16(Bg+(kk)+98304,     lds+8192+(bi)*16384+6144); \
      gl16(Bg+(kk)+114688,    lds+8192+(bi)*16384+7168); \
      gl16(Bg+(kk)+64,        lds+8192+(bi)*16384+8192); \
      gl16(Bg+(kk)+64+16384,  lds+8192+(bi)*16384+9216); \
      gl16(Bg+(kk)+64+32768,  lds+8192+(bi)*16384+10240); \
    } else { \
      gl16(Bg+(kk)+64+49152,  lds+8192+(bi)*16384+11264); \
      gl16(Bg+(kk)+64+65536,  lds+8192+(bi)*16384+12288); \
      gl16(Bg+(kk)+64+81920,  lds+8192+(bi)*16384+13312); \
      gl16(Bg+(kk)+64+98304,  lds+8192+(bi)*16384+14336); \
      gl16(Bg+(kk)+64+114688, lds+8192+(bi)*16384+15360); \
    } \
  }while(0)
  STG_KG(0, 0);
  int cur = 0;
  for (int step = 0; step < 8; ++step){
    if (step < 7) { STG_KG(cur^1, (step+1)*128); VM5; } else { VM0; }
    SBAR; SCHED0;
    const char* A0b = lds + cur*2048;
    const char* A1b = lds + 4096 + cur*2048;
    const char* Bb  = lds + 8192 + cur*16384;
    #pragma unroll
    for (int kf=0; kf<4; kf++){
      int co = kf >> 1, kl = kf & 1;
      i64 a0 = ldA8(A0b + co*1024, lr, kl, lg);
      i64 a1 = ldA8(A1b + co*1024, lr, kl, lg);
      s0 = MFMA8(a0, ONES, s0);
      s1 = MFMA8(a1, ONES, s1);
      #pragma unroll
      for (int nf=0; nf<2; nf++){
        i64 bb = ldA8(Bb + co*8192, w*32 + nf*16 + lr, kl, lg);
        acc0[nf] = MFMA8(a0, bb, acc0[nf]);
        acc1[nf] = MFMA8(a1, bb, acc1[nf]);
      }
    }
    SCHED0; SBAR;
    cur ^= 1;
  }
  #undef STG_KG
  __syncthreads();
  // ---- epilogue: SL[16][392] = [x | Y0 | Y1] ----
  u16* SL = (u16*)lds;
  u16* SLT = (u16*)(lds + 12544);   // [64][16]
  float d0i[4], d1i[4];
  #pragma unroll
  for (int rr=0; rr<4; rr++){
    d1i[rr] = 1.0f / (s0[rr] + 1.0f);   // adj row sums -> d1
    d0i[rr] = 1.0f / (s1[rr] + 1.0f);   // adj col sums -> d0
  }
  #pragma unroll
  for (int nf = 0; nf < 2; nf++) {
    #pragma unroll
    for (int rr = 0; rr < 4; rr++) {
      int rl = lg*4 + rr;
      int row = mt*16 + rl;
      int col = w*32 + nf*16 + lr;
      float xv = (col < 64) ? inp[(size_t)(b*1024+row)*64 + col]
                            : hx [(size_t)(b*1024+row)*64 + (col-64)];
      float y0 = (acc0[nf][rr] + xv) * d0i[rr];
      float y1 = (acc1[nf][rr] + xv) * d1i[rr];
      u16 b0v = f2bf(y0), b1v = f2bf(y1);
      SL[rl*392 + col]       = f2bf(xv);
      SL[rl*392 + 128 + col] = b0v;
      SL[rl*392 + 256 + col] = b1v;
      if (col < 64) {
        size_t grow = (size_t)(b*1024 + row)*384;
        XC2[grow + 128 + col] = b0v;
        XC2[grow + 256 + col] = b1v;
      }
    }
  }
  __syncthreads();
  // ---- gates GEMM: 16x384 @ 384x128 ----
  floatx4 g[2] = {};
  for (int kk = 0; kk < 384; kk += 32) {
    int ko = kk + lg*8;
    bf16x8 a = ldfrag(&SL[(size_t)lr*392 + ko]);
    #pragma unroll
    for (int nf = 0; nf < 2; nf++)
      g[nf] = MFMA16(a, ldfrag(WgT + (size_t)(w*32+nf*16+lr)*384 + ko), g[nf]);
  }
  __syncthreads();
  #pragma unroll
  for (int nf = 0; nf < 2; nf++) {
    #pragma unroll
    for (int rr = 0; rr < 4; rr++) {
      int rl = lg*4 + rr;
      int row = mt*16 + rl;
      int col = w*32 + nf*16 + lr;
      float pre = g[nf][rr] + bias_g[col];
      float s = 1.0f / (1.0f + __expf(-pre));
      if (col < 64) {          // r gate -> S = r*hx
        float shv = s * hx[(size_t)(b*1024+row)*64 + col];
        u16 bv = f2bf(shv);
        XC2[(size_t)(b*1024+row)*384 + 64 + col] = bv;
        SLT[col*16 + rl] = bv;
      } else {                 // u gate
        uBuf[(size_t)(b*1024+row)*64 + (col-64)] = s;
      }
    }
  }
  __syncthreads();
  // Stf8 writeout (feature-major fp8)
  {
    int feat = t >> 2, q = t & 3;
    uint2 vv = *(const uint2*)&SLT[feat*16 + q*4];
    float f0 = bf2f((u16)(vv.x & 0xFFFF)), f1 = bf2f((u16)(vv.x >> 16));
    float f2 = bf2f((u16)(vv.y & 0xFFFF)), f3 = bf2f((u16)(vv.y >> 16));
    *(u32*)(Stf8 + (size_t)b*65536 + (size_t)feat*1024 + mt*16 + q*4) =
      pk4(f0,f1,f2,f3);
  }
}

// ================ KZ2: fp8 Z diffusion + candidate + GRU; 16-row tiles ======
// LDS 24KB: A0 2x2K @0 | A1 2x2K @4096 | B 2x8K @8192
__global__ __launch_bounds__(256) void kz2_cand(
    const u8* __restrict__ adjf8, const u8* __restrict__ adjTf8,
    const u8* __restrict__ Stf8,
    const u16* __restrict__ XC2, const u16* __restrict__ WcT,
    const float* __restrict__ bias_c,
    const float* __restrict__ uBuf, const float* __restrict__ hx,
    float* __restrict__ out){
  __shared__ __align__(16) char lds[24576];
  int bid = ((blockIdx.x & 7) << 7) | (blockIdx.x >> 3);
  int mt = bid & 63, b = bid >> 6;
  int t = threadIdx.x, w = t>>6, l = t&63, lr = l&15, lg = l>>4;
  int gp = (l&7) ^ ((l>>3)&7);
  size_t off = (size_t)(2*(l>>3) + (gp>>2))*1024 + (gp&3)*16;
  const u8* A0g = adjf8  + ((size_t)b<<20) + (size_t)mt*16384 + off;
  const u8* A1g = adjTf8 + ((size_t)b<<20) + (size_t)mt*16384 + off;
  const u8* Bg  = Stf8 + (size_t)b*65536 + off;
  floatx4 z0 = {}, z1 = {}, s0 = {}, s1 = {};
  const i64 ONES = 0x3838383838383838L;
  // per stage 12 gl16 (3/wave)
  #define STG_KZ(bi, kk) do{ \
    if (w==0){ \
      gl16(A0g+(kk),         lds+(bi)*2048); \
      gl16(A0g+(kk)+64,      lds+(bi)*2048+1024); \
      gl16(Bg+(kk),          lds+8192+(bi)*8192); \
    } else if (w==1){ \
      gl16(A1g+(kk),         lds+4096+(bi)*2048); \
      gl16(A1g+(kk)+64,      lds+4096+(bi)*2048+1024); \
      gl16(Bg+(kk)+16384,    lds+8192+(bi)*8192+1024); \
    } else if (w==2){ \
      gl16(Bg+(kk)+32768,    lds+8192+(bi)*8192+2048); \
      gl16(Bg+(kk)+49152,    lds+8192+(bi)*8192+3072); \
      gl16(Bg+(kk)+64,       lds+8192+(bi)*8192+4096); \
    } else { \
      gl16(Bg+(kk)+64+16384, lds+8192+(bi)*8192+5120); \
      gl16(Bg+(kk)+64+32768, lds+8192+(bi)*8192+6144); \
      gl16(Bg+(kk)+64+49152, lds+8192+(bi)*8192+7168); \
    } \
  }while(0)
  STG_KZ(0, 0);
  int cur = 0;
  for (int step = 0; step < 8; ++step){
    if (step < 7) { STG_KZ(cur^1, (step+1)*128); VM3; } else { VM0; }
    SBAR; SCHED0;
    const char* A0b = lds + cur*2048;
    const char* A1b = lds + 4096 + cur*2048;
    const char* Bb  = lds + 8192 + cur*8192;
    #pragma unroll
    for (int kf=0; kf<4; kf++){
      int co = kf >> 1, kl = kf & 1;
      i64 a0 = ldA8(A0b + co*1024, lr, kl, lg);
      i64 a1 = ldA8(A1b + co*1024, lr, kl, lg);
      s0 = MFMA8(a0, ONES, s0);
      s1 = MFMA8(a1, ONES, s1);
      i64 bb = ldA8(Bb + co*4096, w*16 + lr, kl, lg);
      z0 = MFMA8(a0, bb, z0);
      z1 = MFMA8(a1, bb, z1);
    }
    SCHED0; SBAR;
    cur ^= 1;
  }
  #undef STG_KZ
  __syncthreads();
  // ---- SL[16][392] = [x|S | Y0inp|Z0 | Y1inp|Z1]; loader skips Z col ranges
  u16* SL = (u16*)lds;
  {
    int rl = t >> 4, s = t & 15;
    size_t grow = (size_t)(b*1024 + mt*16 + rl)*384;
    size_t base = (size_t)rl*392;
    #pragma unroll
    for (int j = 0; j < 3; j++)            // cols 0..191
      *(uint2*)&SL[base + s*12 + j*4] = *(const uint2*)(XC2 + grow + s*12 + j*4);
    *(uint2*)&SL[base + 256 + s*4] = *(const uint2*)(XC2 + grow + 256 + s*4);
  }
  float d0i[4], d1i[4];
  #pragma unroll
  for (int rr=0; rr<4; rr++){
    d1i[rr] = 1.0f / (s0[rr] + 1.0f);
    d0i[rr] = 1.0f / (s1[rr] + 1.0f);
  }
  __syncthreads();
  #pragma unroll
  for (int rr = 0; rr < 4; rr++) {
    int rl = lg*4 + rr;
    int col = w*16 + lr;
    float sval = bf2f(SL[rl*392 + 64 + col]);
    SL[rl*392 + 192 + col] = f2bf((z0[rr] + sval) * d0i[rr]);
    SL[rl*392 + 320 + col] = f2bf((z1[rr] + sval) * d1i[rr]);
  }
  __syncthreads();
  // ---- candidate GEMM 16x384 @ 384x64 + tanh + GRU ----
  floatx4 c = {};
  for (int kk = 0; kk < 384; kk += 32) {
    int ko = kk + lg*8;
    bf16x8 a = ldfrag(&SL[(size_t)lr*392 + ko]);
    c = MFMA16(a, ldfrag(WcT + (size_t)(w*16+lr)*384 + ko), c);
  }
  #pragma unroll
  for (int rr = 0; rr < 4; rr++) {
    int row = mt*16 + lg*4 + rr;
    int col = w*16 + lr;
    float pre = c[rr] + bias_c[col];
    pre = fminf(fmaxf(pre, -15.f), 15.f);
    float e2 = __expf(2.0f*pre);
    float cv = (e2 - 1.0f) / (e2 + 1.0f);
    float u = uBuf[(size_t)(b*1024+row)*64 + col];
    float h = hx[(size_t)(b*1024+row)*64 + col];
    out[(size_t)(b*1024+row)*64 + col] = u*h + (1.0f - u)*cv;
  }
}

extern "C" void kernel_launch(void* const* d_in, const int* in_sizes, int n_in,
                              void* d_out, int out_size, void* d_ws, size_t ws_size,
                              hipStream_t stream) {
  (void)in_sizes; (void)n_in; (void)out_size; (void)ws_size;
  const float* inp = (const float*)d_in[0];
  const float* hx  = (const float*)d_in[1];
  const float* adj = (const float*)d_in[2];
  const float* W0  = (const float*)d_in[3];
  const float* b0  = (const float*)d_in[4];
  const float* W1  = (const float*)d_in[5];
  const float* b1  = (const float*)d_in[6];
  const float* Wc0 = (const float*)d_in[7];
  const float* bc0 = (const float*)d_in[8];
  const float* Wc1 = (const float*)d_in[9];
  const float* bc1 = (const float*)d_in[10];
  float* out = (float*)d_out;
  char* ws = (char*)d_ws;

  u8* adjf8   = (u8*)(ws + 0);                 // 16777216
  u8* adjTf8  = (u8*)(ws + 16777216);          // 16777216
  u8* Xtf8    = (u8*)(ws + 33554432);          // 2097152
  u16* XC2    = (u16*)(ws + 35651584);         // 12582912
  u8* Stf8    = (u8*)(ws + 48234496);          // 1048576
  float* uBuf = (float*)(ws + 49283072);       // 4194304
  u16* WgT    = (u16*)(ws + 53477376);         // 98304
  u16* WcT    = (u16*)(ws + 53575680);         // 49152
  float* bias_g = (float*)(ws + 53624832);     // 512
  float* bias_c = (float*)(ws + 53625344);     // 256

  hipLaunchKernelGGL(kp3_prep, dim3(4640), dim3(256), 0, stream,
                     inp, hx, adj, W0, b0, W1, b1, Wc0, bc0, Wc1, bc1,
                     WgT, WcT, bias_g, bias_c, adjf8, adjTf8, Xtf8, XC2);
  hipLaunchKernelGGL(kg2_gates, dim3(1024), dim3(256), 0, stream,
                     adjf8, adjTf8, Xtf8, inp, hx, WgT, bias_g, XC2, Stf8, uBuf);
  hipLaunchKernelGGL(kz2_cand, dim3(1024), dim3(256), 0, stream,
                     adjf8, adjTf8, Stf8, XC2, WcT, bias_c, uBuf, hx, out);
}